// Round 6
// baseline (63.812 us; speedup 1.0000x reference)
//
#include <hip/hip_runtime.h>

// Problem constants (match reference setup_inputs)
#define NBAGS 64
#define D 512              // feature dim (floats)
#define D4 128             // feature dim in float4
#define TARGET_CHUNKS 2048 // ~64-row chunks; 8 blocks/CU on 256 CUs
#define GRID1 2112         // 2048 + 64 guard (Sum max(1,floor)+bumps <= 2112 always)

// Apportionment (identical in both kernels, all 32-bit):
//   n_i = max(1, (c_i * 2048) / TT); L = 2048 - sum(n_i) (clamp 0);
//   bags 0..L-1 get +1. Bag i's chunk j covers [rb + c*j/n, rb + c*(j+1)/n).
// Computed lane-parallel in wave 0 (lane i = bag i), broadcast via LDS.
// c*2048 <= 131072*2048 = 2.7e8 < 2^31; c*j <= 131072*2047 < 2^31: int32 safe.

__device__ __forceinline__ int lane_incl_scan(int v, int lane) {
#pragma unroll
    for (int off = 1; off < 64; off <<= 1) {
        int o = __shfl_up(v, off, 64);
        if (lane >= off) v += o;
    }
    return v;
}

// Pass 1: one block per chunk (~64 rows). block = 256 threads.
// thread t: float4 column (t & 127), row parity (t >> 7).
__global__ __launch_bounds__(256) void
agg_partial_kernel(const float* __restrict__ samples,
                   const int* __restrict__ counts,
                   float* __restrict__ partials, int tt) {
    __shared__ int s_bag, s_r0, s_r1;
    const int t = threadIdx.x;
    const int g = blockIdx.x;

    if (t == 0) s_bag = -1;
    if (t < 64) {  // wave 0, lane t = bag t
        const int c = counts[t];
        int n = (c * TARGET_CHUNKS) / tt;          // 32-bit div, one per lane
        if (n < 1) n = 1;
        int S = n;
#pragma unroll
        for (int m = 1; m < 64; m <<= 1) S += __shfl_xor(S, m, 64);
        int L = TARGET_CHUNKS - S; if (L < 0) L = 0;
        n += (t < L) ? 1 : 0;
        const int cb = lane_incl_scan(n, t) - n;   // chunk base (exclusive)
        const int rb = lane_incl_scan(c, t) - c;   // row base (exclusive)
        if (g >= cb && g < cb + n) {               // exactly one lane matches
            const int j = g - cb;
            s_bag = t;
            s_r0 = rb + (c * j) / n;
            s_r1 = rb + (c * (j + 1)) / n;
        }
    }
    __syncthreads();
    if (s_bag < 0) return;                          // guard block past total chunks
    const int r0 = s_r0, r1 = s_r1;

    const int col  = t & (D4 - 1);
    const int half = t >> 7;

    const float4* __restrict__ src = (const float4*)samples;  // row stride D4

    // 8 float4 loads in flight per thread (rows stride 2 within chunk).
    float4 a0 = make_float4(0.f, 0.f, 0.f, 0.f);
    float4 a1 = make_float4(0.f, 0.f, 0.f, 0.f);
    int r = r0 + half;
    for (; r + 14 < r1; r += 16) {
        float4 v0 = src[(r     ) * D4 + col];
        float4 v1 = src[(r +  2) * D4 + col];
        float4 v2 = src[(r +  4) * D4 + col];
        float4 v3 = src[(r +  6) * D4 + col];
        float4 v4 = src[(r +  8) * D4 + col];
        float4 v5 = src[(r + 10) * D4 + col];
        float4 v6 = src[(r + 12) * D4 + col];
        float4 v7 = src[(r + 14) * D4 + col];
        a0.x += v0.x; a0.y += v0.y; a0.z += v0.z; a0.w += v0.w;
        a1.x += v1.x; a1.y += v1.y; a1.z += v1.z; a1.w += v1.w;
        a0.x += v2.x; a0.y += v2.y; a0.z += v2.z; a0.w += v2.w;
        a1.x += v3.x; a1.y += v3.y; a1.z += v3.z; a1.w += v3.w;
        a0.x += v4.x; a0.y += v4.y; a0.z += v4.z; a0.w += v4.w;
        a1.x += v5.x; a1.y += v5.y; a1.z += v5.z; a1.w += v5.w;
        a0.x += v6.x; a0.y += v6.y; a0.z += v6.z; a0.w += v6.w;
        a1.x += v7.x; a1.y += v7.y; a1.z += v7.z; a1.w += v7.w;
    }
    for (; r + 6 < r1; r += 8) {
        float4 v0 = src[(r    ) * D4 + col];
        float4 v1 = src[(r + 2) * D4 + col];
        float4 v2 = src[(r + 4) * D4 + col];
        float4 v3 = src[(r + 6) * D4 + col];
        a0.x += v0.x; a0.y += v0.y; a0.z += v0.z; a0.w += v0.w;
        a1.x += v1.x; a1.y += v1.y; a1.z += v1.z; a1.w += v1.w;
        a0.x += v2.x; a0.y += v2.y; a0.z += v2.z; a0.w += v2.w;
        a1.x += v3.x; a1.y += v3.y; a1.z += v3.z; a1.w += v3.w;
    }
    for (; r < r1; r += 2) {
        float4 v = src[r * D4 + col];
        a0.x += v.x; a0.y += v.y; a0.z += v.z; a0.w += v.w;
    }
    a0.x += a1.x; a0.y += a1.y; a0.z += a1.z; a0.w += a1.w;

    // Combine the two row-parity halves through LDS; half 0 writes out.
    __shared__ float4 lds[D4];
    if (half == 1) lds[col] = a0;
    __syncthreads();
    if (half == 0) {
        float4 o = lds[col];
        a0.x += o.x; a0.y += o.y; a0.z += o.z; a0.w += o.w;
        ((float4*)partials)[g * D4 + col] = a0;
    }
}

// Pass 2: one block per bag; reduce its n chunk partials in fixed order,
// scale by 1/count, write out. grid = NBAGS, block = D4 (128).
__global__ __launch_bounds__(D4) void
agg_reduce_kernel(const float* __restrict__ partials,
                  const int* __restrict__ counts,
                  float* __restrict__ out, int tt) {
    __shared__ int s_cb, s_n;
    const int t   = threadIdx.x;  // 0..127
    const int bag = blockIdx.x;

    if (t < 64) {  // wave 0: same apportionment, lane t = bag t
        const int c = counts[t];
        int n = (c * TARGET_CHUNKS) / tt;
        if (n < 1) n = 1;
        int S = n;
#pragma unroll
        for (int m = 1; m < 64; m <<= 1) S += __shfl_xor(S, m, 64);
        int L = TARGET_CHUNKS - S; if (L < 0) L = 0;
        n += (t < L) ? 1 : 0;
        const int cb = lane_incl_scan(n, t) - n;
        if (t == bag) { s_cb = cb; s_n = n; }
    }
    __syncthreads();
    const int cb = s_cb, n = s_n;

    const float4* __restrict__ p = (const float4*)partials;
    float4 acc = make_float4(0.f, 0.f, 0.f, 0.f);
    for (int k = 0; k < n; ++k) {
        float4 v = p[(cb + k) * D4 + t];
        acc.x += v.x; acc.y += v.y; acc.z += v.z; acc.w += v.w;
    }
    const float inv = 1.0f / (float)counts[bag];
    acc.x *= inv; acc.y *= inv; acc.z *= inv; acc.w *= inv;
    ((float4*)out)[bag * D4 + t] = acc;
}

extern "C" void kernel_launch(void* const* d_in, const int* in_sizes, int n_in,
                              void* d_out, int out_size, void* d_ws, size_t ws_size,
                              hipStream_t stream) {
    const float* samples  = (const float*)d_in[0];
    const int*   counts   = (const int*)d_in[1];   // harness converts int64 -> int32
    float*       out      = (float*)d_out;
    float*       partials = (float*)d_ws;          // GRID1*D floats = 4.3 MiB
    const int    tt       = in_sizes[0] / D;       // total rows (131072)

    agg_partial_kernel<<<GRID1, 256, 0, stream>>>(samples, counts, partials, tt);
    agg_reduce_kernel<<<NBAGS, D4, 0, stream>>>(partials, counts, out, tt);
}

// Round 7
// 53.997 us; speedup vs baseline: 1.1818x; 1.1818x over previous
//
#include <hip/hip_runtime.h>

// Problem constants (match reference setup_inputs)
#define NBAGS 64
#define D 512              // feature dim (floats)
#define D4 128             // feature dim in float4
#define TARGET_CHUNKS 1024 // ~128-row chunks; 4 blocks/CU on 256 CUs
#define GRID1 1088         // headroom: sum of max(1,floor)+bumps <= 1088 always

// Apportionment (all 32-bit):
//   n_i = max(1, (c_i * 1024) / TT); L = 1024 - sum(n_i) (clamp 0);
//   bags 0..L-1 get +1. Bag i's chunk j covers [rb + c*j/n, rb + c*(j+1)/n).
// Computed lane-parallel in wave 0 (lane i = bag i), broadcast via LDS.
// Single fused kernel: each chunk block atomically accumulates its
// (sum * 1/count) contribution straight into d_out (zeroed by memset).

__device__ __forceinline__ int lane_incl_scan(int v, int lane) {
#pragma unroll
    for (int off = 1; off < 64; off <<= 1) {
        int o = __shfl_up(v, off, 64);
        if (lane >= off) v += o;
    }
    return v;
}

// One block per chunk (~128 rows). block = 256 threads.
// thread t: float4 column (t & 127), row parity (t >> 7).
__global__ __launch_bounds__(256) void
agg_fused_kernel(const float* __restrict__ samples,
                 const int* __restrict__ counts,
                 float* __restrict__ out, int tt) {
    __shared__ int s_bag, s_r0, s_r1, s_cnt;
    const int t = threadIdx.x;
    const int g = blockIdx.x;

    if (t == 0) s_bag = -1;
    if (t < 64) {  // wave 0, lane t = bag t
        const int c = counts[t];
        int n = (c * TARGET_CHUNKS) / tt;          // 32-bit div, one per lane
        if (n < 1) n = 1;
        int S = n;
#pragma unroll
        for (int m = 1; m < 64; m <<= 1) S += __shfl_xor(S, m, 64);
        int L = TARGET_CHUNKS - S; if (L < 0) L = 0;
        n += (t < L) ? 1 : 0;
        const int cb = lane_incl_scan(n, t) - n;   // chunk base (exclusive)
        const int rb = lane_incl_scan(c, t) - c;   // row base (exclusive)
        if (g >= cb && g < cb + n) {               // exactly one lane matches
            const int j = g - cb;
            s_bag = t;
            s_cnt = c;
            s_r0 = rb + (c * j) / n;               // c*j < 2^31: int32 safe
            s_r1 = rb + (c * (j + 1)) / n;
        }
    }
    __syncthreads();
    if (s_bag < 0) return;                          // guard block past total chunks
    const int r0 = s_r0, r1 = s_r1;

    const int col  = t & (D4 - 1);
    const int half = t >> 7;

    const float4* __restrict__ src = (const float4*)samples;  // row stride D4

    // 4 float4 loads in flight per thread (rows stride 2 within chunk).
    float4 a0 = make_float4(0.f, 0.f, 0.f, 0.f);
    float4 a1 = make_float4(0.f, 0.f, 0.f, 0.f);
    int r = r0 + half;
    for (; r + 6 < r1; r += 8) {
        float4 v0 = src[(r    ) * D4 + col];
        float4 v1 = src[(r + 2) * D4 + col];
        float4 v2 = src[(r + 4) * D4 + col];
        float4 v3 = src[(r + 6) * D4 + col];
        a0.x += v0.x; a0.y += v0.y; a0.z += v0.z; a0.w += v0.w;
        a1.x += v1.x; a1.y += v1.y; a1.z += v1.z; a1.w += v1.w;
        a0.x += v2.x; a0.y += v2.y; a0.z += v2.z; a0.w += v2.w;
        a1.x += v3.x; a1.y += v3.y; a1.z += v3.z; a1.w += v3.w;
    }
    for (; r < r1; r += 2) {
        float4 v = src[r * D4 + col];
        a0.x += v.x; a0.y += v.y; a0.z += v.z; a0.w += v.w;
    }
    a0.x += a1.x; a0.y += a1.y; a0.z += a1.z; a0.w += a1.w;

    // Combine the two row-parity halves through LDS; half 0 accumulates out.
    __shared__ float4 lds[D4];
    if (half == 1) lds[col] = a0;
    __syncthreads();
    if (half == 0) {
        float4 o = lds[col];
        a0.x += o.x; a0.y += o.y; a0.z += o.z; a0.w += o.w;
        const float inv = 1.0f / (float)s_cnt;
        float* dst = out + s_bag * D + col * 4;
        atomicAdd(dst + 0, a0.x * inv);
        atomicAdd(dst + 1, a0.y * inv);
        atomicAdd(dst + 2, a0.z * inv);
        atomicAdd(dst + 3, a0.w * inv);
    }
}

extern "C" void kernel_launch(void* const* d_in, const int* in_sizes, int n_in,
                              void* d_out, int out_size, void* d_ws, size_t ws_size,
                              hipStream_t stream) {
    const float* samples = (const float*)d_in[0];
    const int*   counts  = (const int*)d_in[1];   // harness converts int64 -> int32
    float*       out     = (float*)d_out;
    const int    tt      = in_sizes[0] / D;       // total rows (131072)

    // Zero the output accumulator (graph-capturable).
    hipMemsetAsync(out, 0, (size_t)out_size * sizeof(float), stream);
    agg_fused_kernel<<<GRID1, 256, 0, stream>>>(samples, counts, out, tt);
}

// Round 8
// 52.152 us; speedup vs baseline: 1.2236x; 1.0354x over previous
//
#include <hip/hip_runtime.h>

// Problem constants (match reference setup_inputs)
#define NBAGS 64
#define D 512          // feature dim (floats)
#define D4 128         // feature dim in float4
#define NCH 1024       // uniform slabs: exactly 4 blocks/CU on 256 CUs

// Block g owns rows [g*tt/NCH, (g+1)*tt/NCH) — EXACTLY uniform work per block
// (128 rows = 256 KiB for tt=131072), independent of bag boundaries.
// Slabs crossing bag boundaries split into sub-segments; each segment's
// column-sum is scaled by 1/count and atomicAdd-ed into out (zeroed by memset).
// Bag prefix sums are computed lane-parallel in wave 0 and shared via LDS.

__device__ __forceinline__ int lane_incl_scan(int v, int lane) {
#pragma unroll
    for (int off = 1; off < 64; off <<= 1) {
        int o = __shfl_up(v, off, 64);
        if (lane >= off) v += o;
    }
    return v;
}

// block = 256 threads. thread t: float4 column (t & 127), row parity (t >> 7).
__global__ __launch_bounds__(256) void
agg_slab_kernel(const float* __restrict__ samples,
                const int* __restrict__ counts,
                float* __restrict__ out, int tt) {
    __shared__ int s_ps[NBAGS + 1];   // row prefix sums: ps[0]=0 .. ps[64]=tt
    __shared__ float4 s_red[D4];      // half-combine buffer

    const int t = threadIdx.x;
    const int g = blockIdx.x;

    if (t == 0) s_ps[0] = 0;
    if (t < 64) {
        const int c = counts[t];
        s_ps[t + 1] = lane_incl_scan(c, t);   // inclusive scan, lane t = bag t
    }
    __syncthreads();

    // Slab bounds (g*tt <= 1023*131072 < 2^31: int32 safe; tt/NCH exact here
    // but the floor formula balances within 1 row regardless).
    const int r0 = (int)(((long long)g * tt) / NCH);
    const int r1 = (int)(((long long)(g + 1) * tt) / NCH);

    const int col  = t & (D4 - 1);
    const int half = t >> 7;
    const float4* __restrict__ src = (const float4*)samples;  // row stride D4

    // Find bag containing r0 (uniform across block; 6-step binary search).
    int k;
    {
        int lo = 0, hi = NBAGS;
        while (hi - lo > 1) {
            int mid = (lo + hi) >> 1;
            if (s_ps[mid] <= r0) lo = mid; else hi = mid;
        }
        k = lo;
    }

    int cur = r0;
    while (cur < r1) {
        const int bend = s_ps[k + 1];
        const int e    = (bend < r1) ? bend : r1;   // segment [cur, e) in bag k

        // 4 float4 loads in flight per thread (rows stride 2 within segment).
        float4 a0 = make_float4(0.f, 0.f, 0.f, 0.f);
        float4 a1 = make_float4(0.f, 0.f, 0.f, 0.f);
        int r = cur + half;
        for (; r + 6 < e; r += 8) {
            float4 v0 = src[(r    ) * D4 + col];
            float4 v1 = src[(r + 2) * D4 + col];
            float4 v2 = src[(r + 4) * D4 + col];
            float4 v3 = src[(r + 6) * D4 + col];
            a0.x += v0.x; a0.y += v0.y; a0.z += v0.z; a0.w += v0.w;
            a1.x += v1.x; a1.y += v1.y; a1.z += v1.z; a1.w += v1.w;
            a0.x += v2.x; a0.y += v2.y; a0.z += v2.z; a0.w += v2.w;
            a1.x += v3.x; a1.y += v3.y; a1.z += v3.z; a1.w += v3.w;
        }
        for (; r < e; r += 2) {
            float4 v = src[r * D4 + col];
            a0.x += v.x; a0.y += v.y; a0.z += v.z; a0.w += v.w;
        }
        a0.x += a1.x; a0.y += a1.y; a0.z += a1.z; a0.w += a1.w;

        // Combine the two row-parity halves; half 0 accumulates into out.
        if (half == 1) s_red[col] = a0;
        __syncthreads();
        if (half == 0) {
            float4 o = s_red[col];
            a0.x += o.x; a0.y += o.y; a0.z += o.z; a0.w += o.w;
            const float inv = 1.0f / (float)(s_ps[k + 1] - s_ps[k]);
            float* dst = out + k * D + col * 4;
            atomicAdd(dst + 0, a0.x * inv);
            atomicAdd(dst + 1, a0.y * inv);
            atomicAdd(dst + 2, a0.z * inv);
            atomicAdd(dst + 3, a0.w * inv);
        }
        __syncthreads();   // protect s_red before next segment reuses it
        cur = e;
        ++k;
    }
}

extern "C" void kernel_launch(void* const* d_in, const int* in_sizes, int n_in,
                              void* d_out, int out_size, void* d_ws, size_t ws_size,
                              hipStream_t stream) {
    const float* samples = (const float*)d_in[0];
    const int*   counts  = (const int*)d_in[1];   // harness converts int64 -> int32
    float*       out     = (float*)d_out;
    const int    tt      = in_sizes[0] / D;       // total rows (131072)

    // Zero the output accumulator (graph-capturable).
    hipMemsetAsync(out, 0, (size_t)out_size * sizeof(float), stream);
    agg_slab_kernel<<<NCH, 256, 0, stream>>>(samples, counts, out, tt);
}